// Round 14
// baseline (46.428 us; speedup 1.0000x reference)
//
#include <hip/hip_runtime.h>

typedef _Float16     f16x8  __attribute__((ext_vector_type(8)));
typedef float        f32x4  __attribute__((ext_vector_type(4)));
typedef float        f32x16 __attribute__((ext_vector_type(16)));
typedef unsigned int u32x4  __attribute__((ext_vector_type(4)));

#define BATCH 65536
#define NIN   128
#define NOUT  128

#define L2E   1.4426950408889634f
#define SQL2E 1.2011224087864498f     /* sqrt(log2 e) */
#define EM2   0.1353352832366127f     /* e^-2 */

// ---------------------------------------------------------------------------
// R14: NO LDS, NO BARRIERS. W3 (288 KB) is L2-resident per XCD; every wave
// reads B-fragments directly from global with one coalesced
// global_load_dwordx4 per fragment (64 lanes x 16 B consecutive).
//
// MFMA 32x32x16 f16. A-frag: lane -> row = l&31, k = (l>>5)*8 + e.
// B-frag: lane -> col = l&31, k = (l>>5)*8 + e. C/D: col = l&31,
// row = (reg&3) + 8*(reg>>2) + 4*(l>>5).
//
// K-order (72 ksteps of 16): basis ks = g*8 + t2 (g=0..7):
//   k-slot sub*8+e -> j = g*16 + sub*8 + t2, grid = e
//   (lane consumes 8 CONSECUTIVE x floats per group). silu ks = 64+s:
//   j = s*16 + sub*8 + e.
//
// W3 (kan_prep, unchanged): 72 tiles x 4 KB; tile ks, chunk c = nbb*64+lane:
//   col = nbb*32 + (lane&31), sub = lane>>5:
//     ks < 64 : coeffs[col][(ks>>3)*16 + sub*8 + (ks&7)][e]
//     ks >= 64: base_w[col][(ks-64)*16 + sub*8 + e]
//
// Wave = 64 rows x 64 cols (m=2, q=2): each B-fragment feeds 2 MFMAs, so
// L2 B-traffic = 2048 waves x 144 KB = 295 MB (~8.6 us at L2 agg BW).
// 256-thr blocks = 4 fully independent waves; grid 512 (2 blocks/CU).
// ---------------------------------------------------------------------------

__global__ __launch_bounds__(256) void kan_prep(const float* __restrict__ coeffs,
                                                const float* __restrict__ base_w,
                                                _Float16* __restrict__ W3) {
    int t = blockIdx.x * 256 + threadIdx.x;   // chunk id, 0..18431
    int ks   = t >> 8;
    int c    = t & 255;
    int nbb  = c >> 6;
    int lane = c & 63;
    int sub  = lane >> 5;
    int col  = nbb * 32 + (lane & 31);
    f16x8 v;
    if (ks < 64) {
        int g = ks >> 3, t2 = ks & 7;
        const float* src = coeffs + ((size_t)col * 128 + g * 16 + sub * 8 + t2) * 8;
#pragma unroll
        for (int e = 0; e < 8; ++e) v[e] = (_Float16)src[e];
    } else {
        const float* src = base_w + (size_t)col * 128 + (ks - 64) * 16 + sub * 8;
#pragma unroll
        for (int e = 0; e < 8; ++e) v[e] = (_Float16)src[e];
    }
    *(f16x8*)((char*)W3 + (size_t)t * 16) = v;
}

// b_g = exp(-(t-g)^2), t = 3.5*(x+1): 2 exp + mul chain; dword-packed result.
__device__ __forceinline__ f16x8 basis8r(float t) {
    float u  = t * SQL2E;
    float b0 = __builtin_amdgcn_exp2f(-(u * u));                              // e^{-t^2}
    float r  = __builtin_amdgcn_exp2f(__builtin_fmaf(t, 2.0f * L2E, -L2E));   // e^{2t-1}
    float b1 = b0 * r; r *= EM2;
    float b2 = b1 * r; r *= EM2;
    float b3 = b2 * r; r *= EM2;
    float b4 = b3 * r; r *= EM2;
    float b5 = b4 * r; r *= EM2;
    float b6 = b5 * r; r *= EM2;
    float b7 = b6 * r;
    u32x4 U;
    U[0] = __builtin_bit_cast(unsigned int, __builtin_amdgcn_cvt_pkrtz(b0, b1));
    U[1] = __builtin_bit_cast(unsigned int, __builtin_amdgcn_cvt_pkrtz(b2, b3));
    U[2] = __builtin_bit_cast(unsigned int, __builtin_amdgcn_cvt_pkrtz(b4, b5));
    U[3] = __builtin_bit_cast(unsigned int, __builtin_amdgcn_cvt_pkrtz(b6, b7));
    return __builtin_bit_cast(f16x8, U);
}

__device__ __forceinline__ float silu1(float xv) {
    float p = __builtin_amdgcn_exp2f(-xv * L2E);
    return xv * __builtin_amdgcn_rcpf(1.0f + p);
}

// 256 threads = 4 INDEPENDENT waves (no barrier, no LDS). Wave w owns rows
// [blockRow + w*64, +64) x cols [h*64, +64). Grid 512: 2 blocks/CU.
__global__ __launch_bounds__(256, 2) void kan_main(const float* __restrict__ x,
                                                   const _Float16* __restrict__ W3,
                                                   float* __restrict__ out) {
    const int tid  = threadIdx.x;
    const int lane = tid & 63;
    const int w    = tid >> 6;
    const int l31  = lane & 31;
    const int sub  = lane >> 5;
    const int h    = blockIdx.x & 1;                       // col half
    const int row0 = (blockIdx.x >> 1) * 256 + w * 64;     // wave's 64 rows
    const int col0 = h * 64;

    // lane's x rows: m=0 -> row0+l31, m=1 -> row0+32+l31
    const float* xp = x + (size_t)(row0 + l31) * NIN;
    const char*  wb = (const char*)W3 + col0 * 32 + lane * 16;  // h*2 chunks of 1 KB

    f32x16 acc[2][2];
#pragma unroll
    for (int m = 0; m < 2; ++m)
#pragma unroll
        for (int q = 0; q < 2; ++q)
#pragma unroll
            for (int r = 0; r < 16; ++r) acc[m][q][r] = 0.f;

    // group-0 x
    f32x4 xa0 = *(const f32x4*)(xp + sub * 8);
    f32x4 xa1 = *(const f32x4*)(xp + sub * 8 + 4);
    f32x4 xb0 = *(const f32x4*)(xp + 16 * 256 + sub * 8);          // +32 rows
    f32x4 xb1 = *(const f32x4*)(xp + 16 * 256 + sub * 8 + 4);

    // ---- 8 basis groups of 8 ksteps (K = 1024) ----
#pragma unroll
    for (int g = 0; g < 8; ++g) {
        // prefetch next group's x (g=7 -> silu s=0 x, same as group 0... col 0)
        const int nxt = (g < 7) ? (g + 1) * 16 : 0;
        f32x4 na0 = *(const f32x4*)(xp + nxt + sub * 8);
        f32x4 na1 = *(const f32x4*)(xp + nxt + sub * 8 + 4);
        f32x4 nb0 = *(const f32x4*)(xp + 4096 + nxt + sub * 8);
        f32x4 nb1 = *(const f32x4*)(xp + 4096 + nxt + sub * 8 + 4);

        // pregenerate the group's A-fragments: 8 per m (16 indep chains)
        f16x8 aA[8], aB[8];
#pragma unroll
        for (int t2 = 0; t2 < 4; ++t2) {
            aA[t2]     = basis8r(__builtin_fmaf(xa0[t2], 3.5f, 3.5f));
            aA[4 + t2] = basis8r(__builtin_fmaf(xa1[t2], 3.5f, 3.5f));
            aB[t2]     = basis8r(__builtin_fmaf(xb0[t2], 3.5f, 3.5f));
            aB[4 + t2] = basis8r(__builtin_fmaf(xb1[t2], 3.5f, 3.5f));
        }

        // MFMA stream: per kstep, 2 direct-from-L2 B loads feed 4 MFMAs
#pragma unroll
        for (int t2 = 0; t2 < 8; ++t2) {
            const char* bp = wb + (size_t)(g * 8 + t2) * 4096;
            f16x8 b0 = *(const f16x8*)bp;
            f16x8 b1 = *(const f16x8*)(bp + 1024);
            acc[0][0] = __builtin_amdgcn_mfma_f32_32x32x16_f16(aA[t2], b0, acc[0][0], 0, 0, 0);
            acc[0][1] = __builtin_amdgcn_mfma_f32_32x32x16_f16(aA[t2], b1, acc[0][1], 0, 0, 0);
            acc[1][0] = __builtin_amdgcn_mfma_f32_32x32x16_f16(aB[t2], b0, acc[1][0], 0, 0, 0);
            acc[1][1] = __builtin_amdgcn_mfma_f32_32x32x16_f16(aB[t2], b1, acc[1][1], 0, 0, 0);
        }
        xa0 = na0; xa1 = na1; xb0 = nb0; xb1 = nb1;
    }

    // ---- silu group: 8 ksteps (K = 128), tiles 64..71 ----
#pragma unroll
    for (int s = 0; s < 8; ++s) {
        f32x4 na0, na1, nb0, nb1;
        if (s < 7) {
            na0 = *(const f32x4*)(xp + (s + 1) * 16 + sub * 8);
            na1 = *(const f32x4*)(xp + (s + 1) * 16 + sub * 8 + 4);
            nb0 = *(const f32x4*)(xp + 4096 + (s + 1) * 16 + sub * 8);
            nb1 = *(const f32x4*)(xp + 4096 + (s + 1) * 16 + sub * 8 + 4);
        }
        u32x4 UA, UB;
        UA[0] = __builtin_bit_cast(unsigned int,
                __builtin_amdgcn_cvt_pkrtz(silu1(xa0[0]), silu1(xa0[1])));
        UA[1] = __builtin_bit_cast(unsigned int,
                __builtin_amdgcn_cvt_pkrtz(silu1(xa0[2]), silu1(xa0[3])));
        UA[2] = __builtin_bit_cast(unsigned int,
                __builtin_amdgcn_cvt_pkrtz(silu1(xa1[0]), silu1(xa1[1])));
        UA[3] = __builtin_bit_cast(unsigned int,
                __builtin_amdgcn_cvt_pkrtz(silu1(xa1[2]), silu1(xa1[3])));
        UB[0] = __builtin_bit_cast(unsigned int,
                __builtin_amdgcn_cvt_pkrtz(silu1(xb0[0]), silu1(xb0[1])));
        UB[1] = __builtin_bit_cast(unsigned int,
                __builtin_amdgcn_cvt_pkrtz(silu1(xb0[2]), silu1(xb0[3])));
        UB[2] = __builtin_bit_cast(unsigned int,
                __builtin_amdgcn_cvt_pkrtz(silu1(xb1[0]), silu1(xb1[1])));
        UB[3] = __builtin_bit_cast(unsigned int,
                __builtin_amdgcn_cvt_pkrtz(silu1(xb1[2]), silu1(xb1[3])));
        f16x8 aA = __builtin_bit_cast(f16x8, UA);
        f16x8 aB = __builtin_bit_cast(f16x8, UB);
        const char* bp = wb + (size_t)(64 + s) * 4096;
        f16x8 b0 = *(const f16x8*)bp;
        f16x8 b1 = *(const f16x8*)(bp + 1024);
        acc[0][0] = __builtin_amdgcn_mfma_f32_32x32x16_f16(aA, b0, acc[0][0], 0, 0, 0);
        acc[0][1] = __builtin_amdgcn_mfma_f32_32x32x16_f16(aA, b1, acc[0][1], 0, 0, 0);
        acc[1][0] = __builtin_amdgcn_mfma_f32_32x32x16_f16(aB, b0, acc[1][0], 0, 0, 0);
        acc[1][1] = __builtin_amdgcn_mfma_f32_32x32x16_f16(aB, b1, acc[1][1], 0, 0, 0);
        if (s < 7) { xa0 = na0; xa1 = na1; xb0 = nb0; xb1 = nb1; }
    }

    // ---- Epilogue: row = m*32 + (r&3) + 8*(r>>2) + 4*sub, col = col0+q*32+l31
#pragma unroll
    for (int m = 0; m < 2; ++m)
#pragma unroll
        for (int q = 0; q < 2; ++q)
#pragma unroll
            for (int r = 0; r < 16; ++r) {
                int crow = (r & 3) + 8 * (r >> 2) + 4 * sub;
                out[(size_t)(row0 + m * 32 + crow) * NOUT + col0 + q * 32 + l31] =
                    acc[m][q][r];
            }
}

extern "C" void kernel_launch(void* const* d_in, const int* in_sizes, int n_in,
                              void* d_out, int out_size, void* d_ws, size_t ws_size,
                              hipStream_t stream) {
    const float* x       = (const float*)d_in[0];
    const float* coeffs  = (const float*)d_in[1];
    const float* base_w  = (const float*)d_in[2];
    _Float16* W3 = (_Float16*)d_ws;   // 72 * 4096 = 294912 bytes

    kan_prep<<<dim3(72), dim3(256), 0, stream>>>(coeffs, base_w, W3);
    kan_main<<<dim3(BATCH / 128), dim3(256), 0, stream>>>(x, W3, (float*)d_out);
}

// Round 15
// 46.060 us; speedup vs baseline: 1.0080x; 1.0080x over previous
//
#include <hip/hip_runtime.h>

typedef _Float16     f16x8  __attribute__((ext_vector_type(8)));
typedef float        f32x4  __attribute__((ext_vector_type(4)));
typedef float        f32x16 __attribute__((ext_vector_type(16)));
typedef unsigned int u32x4  __attribute__((ext_vector_type(4)));

#define BATCH 65536
#define NIN   128
#define NOUT  128

#define L2E   1.4426950408889634f
#define SQL2E 1.2011224087864498f     /* sqrt(log2 e) */
#define EM2   0.1353352832366127f     /* e^-2 */

// ---------------------------------------------------------------------------
// R15 = R14 (no LDS, no barriers, L2-direct B) + DEEP EXPLICIT PIPELINING:
// all 16 B-fragment loads of a group are issued BEFORE the ~700-cyc a-gen
// burst, so their ~300-cyc L2 latency is fully hidden; next-group x loads
// are issued before the 1024-cyc MFMA stream. R14's VGPR=128 showed the
// compiler scheduled loads just-before-use (per-t2 ~300 cyc exposed).
//
// MFMA 32x32x16 f16. A-frag: lane -> row = l&31, k = (l>>5)*8 + e.
// B-frag: lane -> col = l&31, k = (l>>5)*8 + e. C/D: col = l&31,
// row = (reg&3) + 8*(reg>>2) + 4*(l>>5).
//
// K-order (72 ksteps of 16): basis ks = g*8 + t2 (g=0..7):
//   k-slot sub*8+e -> j = g*16 + sub*8 + t2, grid = e
//   (lane consumes 8 CONSECUTIVE x floats per group). silu ks = 64+s:
//   j = s*16 + sub*8 + e.
//
// W3 (kan_prep, unchanged): 72 tiles x 4 KB; tile ks, chunk c = nbb*64+lane:
//   col = nbb*32 + (lane&31), sub = lane>>5:
//     ks < 64 : coeffs[col][(ks>>3)*16 + sub*8 + (ks&7)][e]
//     ks >= 64: base_w[col][(ks-64)*16 + sub*8 + e]
//
// Wave = 64 rows x 64 cols (m=2, q=2); 256-thr blocks = 4 independent waves;
// grid 512 (2 blocks/CU, 2 waves/SIMD, <=256 VGPR).
// ---------------------------------------------------------------------------

__global__ __launch_bounds__(256) void kan_prep(const float* __restrict__ coeffs,
                                                const float* __restrict__ base_w,
                                                _Float16* __restrict__ W3) {
    int t = blockIdx.x * 256 + threadIdx.x;   // chunk id, 0..18431
    int ks   = t >> 8;
    int c    = t & 255;
    int nbb  = c >> 6;
    int lane = c & 63;
    int sub  = lane >> 5;
    int col  = nbb * 32 + (lane & 31);
    f16x8 v;
    if (ks < 64) {
        int g = ks >> 3, t2 = ks & 7;
        const float* src = coeffs + ((size_t)col * 128 + g * 16 + sub * 8 + t2) * 8;
#pragma unroll
        for (int e = 0; e < 8; ++e) v[e] = (_Float16)src[e];
    } else {
        const float* src = base_w + (size_t)col * 128 + (ks - 64) * 16 + sub * 8;
#pragma unroll
        for (int e = 0; e < 8; ++e) v[e] = (_Float16)src[e];
    }
    *(f16x8*)((char*)W3 + (size_t)t * 16) = v;
}

// b_g = exp(-(t-g)^2), t = 3.5*(x+1): 2 exp + mul chain; dword-packed result.
__device__ __forceinline__ f16x8 basis8r(float t) {
    float u  = t * SQL2E;
    float b0 = __builtin_amdgcn_exp2f(-(u * u));                              // e^{-t^2}
    float r  = __builtin_amdgcn_exp2f(__builtin_fmaf(t, 2.0f * L2E, -L2E));   // e^{2t-1}
    float b1 = b0 * r; r *= EM2;
    float b2 = b1 * r; r *= EM2;
    float b3 = b2 * r; r *= EM2;
    float b4 = b3 * r; r *= EM2;
    float b5 = b4 * r; r *= EM2;
    float b6 = b5 * r; r *= EM2;
    float b7 = b6 * r;
    u32x4 U;
    U[0] = __builtin_bit_cast(unsigned int, __builtin_amdgcn_cvt_pkrtz(b0, b1));
    U[1] = __builtin_bit_cast(unsigned int, __builtin_amdgcn_cvt_pkrtz(b2, b3));
    U[2] = __builtin_bit_cast(unsigned int, __builtin_amdgcn_cvt_pkrtz(b4, b5));
    U[3] = __builtin_bit_cast(unsigned int, __builtin_amdgcn_cvt_pkrtz(b6, b7));
    return __builtin_bit_cast(f16x8, U);
}

__device__ __forceinline__ float silu1(float xv) {
    float p = __builtin_amdgcn_exp2f(-xv * L2E);
    return xv * __builtin_amdgcn_rcpf(1.0f + p);
}

// 256 threads = 4 INDEPENDENT waves (no barrier, no LDS). Wave w owns rows
// [blockRow + w*64, +64) x cols [h*64, +64). Grid 512: 2 blocks/CU.
__global__ __launch_bounds__(256, 2) void kan_main(const float* __restrict__ x,
                                                   const _Float16* __restrict__ W3,
                                                   float* __restrict__ out) {
    const int tid  = threadIdx.x;
    const int lane = tid & 63;
    const int w    = tid >> 6;
    const int l31  = lane & 31;
    const int sub  = lane >> 5;
    const int h    = blockIdx.x & 1;                       // col half
    const int row0 = (blockIdx.x >> 1) * 256 + w * 64;     // wave's 64 rows
    const int col0 = h * 64;

    // lane's x rows: m=0 -> row0+l31, m=1 -> row0+32+l31 (+4096 floats)
    const float* xp = x + (size_t)(row0 + l31) * NIN;
    const char*  wb = (const char*)W3 + col0 * 32 + lane * 16;

    f32x16 acc[2][2];
#pragma unroll
    for (int m = 0; m < 2; ++m)
#pragma unroll
        for (int q = 0; q < 2; ++q)
#pragma unroll
            for (int r = 0; r < 16; ++r) acc[m][q][r] = 0.f;

    // group-0 x
    f32x4 xa0 = *(const f32x4*)(xp + sub * 8);
    f32x4 xa1 = *(const f32x4*)(xp + sub * 8 + 4);
    f32x4 xb0 = *(const f32x4*)(xp + 4096 + sub * 8);
    f32x4 xb1 = *(const f32x4*)(xp + 4096 + sub * 8 + 4);

    // ---- 8 basis groups of 8 ksteps (K = 1024) ----
#pragma unroll
    for (int g = 0; g < 8; ++g) {
        // (1) issue ALL 16 B-fragment loads for this group (64 VGPR in flight)
        f16x8 bl[16];
#pragma unroll
        for (int t2 = 0; t2 < 8; ++t2) {
            const char* bp = wb + (size_t)(g * 8 + t2) * 4096;
            bl[2 * t2]     = *(const f16x8*)bp;
            bl[2 * t2 + 1] = *(const f16x8*)(bp + 1024);
        }

        // (2) a-gen burst (~700 cyc) hides the B-load latency
        f16x8 aA[8], aB[8];
#pragma unroll
        for (int t2 = 0; t2 < 4; ++t2) {
            aA[t2]     = basis8r(__builtin_fmaf(xa0[t2], 3.5f, 3.5f));
            aA[4 + t2] = basis8r(__builtin_fmaf(xa1[t2], 3.5f, 3.5f));
            aB[t2]     = basis8r(__builtin_fmaf(xb0[t2], 3.5f, 3.5f));
            aB[4 + t2] = basis8r(__builtin_fmaf(xb1[t2], 3.5f, 3.5f));
        }

        // (3) next group's x loads: latency hidden by the MFMA stream
        const int nxt = (g < 7) ? (g + 1) * 16 : 0;   // g==7 -> silu s=0 x
        f32x4 na0 = *(const f32x4*)(xp + nxt + sub * 8);
        f32x4 na1 = *(const f32x4*)(xp + nxt + sub * 8 + 4);
        f32x4 nb0 = *(const f32x4*)(xp + 4096 + nxt + sub * 8);
        f32x4 nb1 = *(const f32x4*)(xp + 4096 + nxt + sub * 8 + 4);

        // (4) MFMA stream: 32 MFMAs, operands already resident
#pragma unroll
        for (int t2 = 0; t2 < 8; ++t2) {
            acc[0][0] = __builtin_amdgcn_mfma_f32_32x32x16_f16(aA[t2], bl[2 * t2],     acc[0][0], 0, 0, 0);
            acc[0][1] = __builtin_amdgcn_mfma_f32_32x32x16_f16(aA[t2], bl[2 * t2 + 1], acc[0][1], 0, 0, 0);
            acc[1][0] = __builtin_amdgcn_mfma_f32_32x32x16_f16(aB[t2], bl[2 * t2],     acc[1][0], 0, 0, 0);
            acc[1][1] = __builtin_amdgcn_mfma_f32_32x32x16_f16(aB[t2], bl[2 * t2 + 1], acc[1][1], 0, 0, 0);
        }
        xa0 = na0; xa1 = na1; xb0 = nb0; xb1 = nb1;
    }

    // ---- silu group: 8 ksteps (K = 128); pre-issue all 16 B fragments ----
    f16x8 sbl[16];
#pragma unroll
    for (int s = 0; s < 8; ++s) {
        const char* bp = wb + (size_t)(64 + s) * 4096;
        sbl[2 * s]     = *(const f16x8*)bp;
        sbl[2 * s + 1] = *(const f16x8*)(bp + 1024);
    }
#pragma unroll
    for (int s = 0; s < 8; ++s) {
        f32x4 na0, na1, nb0, nb1;
        if (s < 7) {   // x rolls 1 kstep ahead (L1/L2-resident by now)
            na0 = *(const f32x4*)(xp + (s + 1) * 16 + sub * 8);
            na1 = *(const f32x4*)(xp + (s + 1) * 16 + sub * 8 + 4);
            nb0 = *(const f32x4*)(xp + 4096 + (s + 1) * 16 + sub * 8);
            nb1 = *(const f32x4*)(xp + 4096 + (s + 1) * 16 + sub * 8 + 4);
        }
        u32x4 UA, UB;
        UA[0] = __builtin_bit_cast(unsigned int,
                __builtin_amdgcn_cvt_pkrtz(silu1(xa0[0]), silu1(xa0[1])));
        UA[1] = __builtin_bit_cast(unsigned int,
                __builtin_amdgcn_cvt_pkrtz(silu1(xa0[2]), silu1(xa0[3])));
        UA[2] = __builtin_bit_cast(unsigned int,
                __builtin_amdgcn_cvt_pkrtz(silu1(xa1[0]), silu1(xa1[1])));
        UA[3] = __builtin_bit_cast(unsigned int,
                __builtin_amdgcn_cvt_pkrtz(silu1(xa1[2]), silu1(xa1[3])));
        UB[0] = __builtin_bit_cast(unsigned int,
                __builtin_amdgcn_cvt_pkrtz(silu1(xb0[0]), silu1(xb0[1])));
        UB[1] = __builtin_bit_cast(unsigned int,
                __builtin_amdgcn_cvt_pkrtz(silu1(xb0[2]), silu1(xb0[3])));
        UB[2] = __builtin_bit_cast(unsigned int,
                __builtin_amdgcn_cvt_pkrtz(silu1(xb1[0]), silu1(xb1[1])));
        UB[3] = __builtin_bit_cast(unsigned int,
                __builtin_amdgcn_cvt_pkrtz(silu1(xb1[2]), silu1(xb1[3])));
        f16x8 aA = __builtin_bit_cast(f16x8, UA);
        f16x8 aB = __builtin_bit_cast(f16x8, UB);
        acc[0][0] = __builtin_amdgcn_mfma_f32_32x32x16_f16(aA, sbl[2 * s],     acc[0][0], 0, 0, 0);
        acc[0][1] = __builtin_amdgcn_mfma_f32_32x32x16_f16(aA, sbl[2 * s + 1], acc[0][1], 0, 0, 0);
        acc[1][0] = __builtin_amdgcn_mfma_f32_32x32x16_f16(aB, sbl[2 * s],     acc[1][0], 0, 0, 0);
        acc[1][1] = __builtin_amdgcn_mfma_f32_32x32x16_f16(aB, sbl[2 * s + 1], acc[1][1], 0, 0, 0);
        if (s < 7) { xa0 = na0; xa1 = na1; xb0 = nb0; xb1 = nb1; }
    }

    // ---- Epilogue: row = m*32 + (r&3) + 8*(r>>2) + 4*sub, col = col0+q*32+l31
#pragma unroll
    for (int m = 0; m < 2; ++m)
#pragma unroll
        for (int q = 0; q < 2; ++q)
#pragma unroll
            for (int r = 0; r < 16; ++r) {
                int crow = (r & 3) + 8 * (r >> 2) + 4 * sub;
                out[(size_t)(row0 + m * 32 + crow) * NOUT + col0 + q * 32 + l31] =
                    acc[m][q][r];
            }
}

extern "C" void kernel_launch(void* const* d_in, const int* in_sizes, int n_in,
                              void* d_out, int out_size, void* d_ws, size_t ws_size,
                              hipStream_t stream) {
    const float* x       = (const float*)d_in[0];
    const float* coeffs  = (const float*)d_in[1];
    const float* base_w  = (const float*)d_in[2];
    _Float16* W3 = (_Float16*)d_ws;   // 72 * 4096 = 294912 bytes

    kan_prep<<<dim3(72), dim3(256), 0, stream>>>(coeffs, base_w, W3);
    kan_main<<<dim3(BATCH / 128), dim3(256), 0, stream>>>(x, W3, (float*)d_out);
}